// Round 3
// baseline (2437.832 us; speedup 1.0000x reference)
//
#include <hip/hip_runtime.h>

#define NPTS 8192
#define NB 4
#define CH 64
#define KNN 16

__device__ __forceinline__ float bf2f(unsigned short u) {
    return __uint_as_float(((unsigned)u) << 16);
}
__device__ __forceinline__ unsigned short f2bf(float f) {
    unsigned u = __float_as_uint(f);
    u += 0x7fffu + ((u >> 16) & 1u);
    return (unsigned short)(u >> 16);
}

// ---------------- top-16 sorted insertion (strict <: lower-index-first on ties) ----
#define INSERT16(cd, ci, dist, idx)                         \
    {                                                       \
        float _cd = (cd); int _ci = (ci);                   \
        _Pragma("unroll")                                   \
        for (int m = 0; m < KNN; ++m) {                     \
            const bool sw = _cd < dist[m];                  \
            const float td = sw ? dist[m] : _cd;            \
            const int   ti = sw ? idx[m] : _ci;             \
            dist[m] = sw ? _cd : dist[m];                   \
            idx[m]  = sw ? _ci : idx[m];                    \
            _cd = td; _ci = ti;                             \
        }                                                   \
    }

// ---------------- Kernel 1a: partial KNN over one candidate segment ----------------
template <int S>
__global__ __launch_bounds__(128) void knn_part_kernel(const float* __restrict__ pts,
                                                       float* __restrict__ pdist,
                                                       int* __restrict__ pidx) {
    __shared__ float4 tile[128];
    const int q = blockIdx.x * 128 + threadIdx.x;   // 0..32767
    const int s = blockIdx.y;                       // segment
    const int b = q >> 13;
    const int n = q & (NPTS - 1);
    const float* pb = pts + (size_t)b * NPTS * 3;

    const float px = pb[n * 3 + 0];
    const float py = pb[n * 3 + 1];
    const float pz = pb[n * 3 + 2];
    const float sqi = (px * px + py * py) + pz * pz;

    float dist[KNN];
    int   idx[KNN];
#pragma unroll
    for (int m = 0; m < KNN; ++m) { dist[m] = 3.4e38f; idx[m] = 0; }

    const int CS = NPTS / S;
    const int base = s * CS;
    for (int t = 0; t < CS / 128; ++t) {
        const int j0 = base + t * 128;
        {
            const int c = j0 + threadIdx.x;
            const float x = pb[c * 3 + 0];
            const float y = pb[c * 3 + 1];
            const float z = pb[c * 3 + 2];
            tile[threadIdx.x] = make_float4(x, y, z, (x * x + y * y) + z * z);
        }
        __syncthreads();
#pragma unroll 8
        for (int jj = 0; jj < 128; ++jj) {
            const float4 v = tile[jj];
            float dot = px * v.x;
            dot = fmaf(py, v.y, dot);
            dot = fmaf(pz, v.z, dot);
            // d = (sq_i + sq_j) - 2*dot ; 2*dot exact so fma == separate rounding
            const float d = fmaf(dot, -2.0f, sqi + v.w);
            if (d < dist[KNN - 1]) {
                INSERT16(d, j0 + jj, dist, idx);
            }
        }
        __syncthreads();
    }
    float* pd = pdist + ((size_t)q * S + s) * KNN;
    int*   pi = pidx  + ((size_t)q * S + s) * KNN;
#pragma unroll
    for (int m = 0; m < KNN; ++m) { pd[m] = dist[m]; pi[m] = idx[m]; }
}

// ---------------- Kernel 1b: merge S sorted 16-lists per query ----------------
// Segments merged in ascending order: every incoming index exceeds all resident
// indices, so strict-< insertion reproduces top_k's (value, lower-index) order.
template <int S>
__global__ __launch_bounds__(256) void knn_merge_kernel(const float* __restrict__ pdist,
                                                        const int* __restrict__ pidx,
                                                        int* __restrict__ idx_out) {
    const int q = blockIdx.x * 256 + threadIdx.x;   // 0..32767
    const float* pd = pdist + (size_t)q * S * KNN;
    const int*   pi = pidx  + (size_t)q * S * KNN;

    float dist[KNN];
    int   idx[KNN];
#pragma unroll
    for (int m = 0; m < KNN; ++m) { dist[m] = pd[m]; idx[m] = pi[m]; }

    for (int s = 1; s < S; ++s) {
#pragma unroll
        for (int e = 0; e < KNN; ++e) {
            const float d = pd[s * KNN + e];
            const int  ci = pi[s * KNN + e];
            if (d < dist[KNN - 1]) {
                INSERT16(d, ci, dist, idx);
            }
        }
    }
    int* op = idx_out + (size_t)q * KNN;
#pragma unroll
    for (int m = 0; m < KNN; ++m) op[m] = idx[m];
}

// ---------------- Kernel 1 fallback: full-scan KNN (small ws) ----------------
__global__ __launch_bounds__(128) void knn_full_kernel(const float* __restrict__ pts,
                                                       int* __restrict__ idx_out) {
    __shared__ float4 tile[128];
    const int q = blockIdx.x * 128 + threadIdx.x;
    const int b = q >> 13;
    const int n = q & (NPTS - 1);
    const float* pb = pts + (size_t)b * NPTS * 3;

    const float px = pb[n * 3 + 0];
    const float py = pb[n * 3 + 1];
    const float pz = pb[n * 3 + 2];
    const float sqi = (px * px + py * py) + pz * pz;

    float dist[KNN];
    int   idx[KNN];
#pragma unroll
    for (int m = 0; m < KNN; ++m) { dist[m] = 3.4e38f; idx[m] = 0; }

    for (int t = 0; t < NPTS / 128; ++t) {
        const int j0 = t * 128;
        {
            const int c = j0 + threadIdx.x;
            const float x = pb[c * 3 + 0];
            const float y = pb[c * 3 + 1];
            const float z = pb[c * 3 + 2];
            tile[threadIdx.x] = make_float4(x, y, z, (x * x + y * y) + z * z);
        }
        __syncthreads();
#pragma unroll 4
        for (int jj = 0; jj < 128; ++jj) {
            const float4 v = tile[jj];
            float dot = px * v.x;
            dot = fmaf(py, v.y, dot);
            dot = fmaf(pz, v.z, dot);
            const float d = fmaf(dot, -2.0f, sqi + v.w);
            if (d < dist[KNN - 1]) {
                INSERT16(d, j0 + jj, dist, idx);
            }
        }
        __syncthreads();
    }
    int* op = idx_out + (size_t)q * KNN;
#pragma unroll
    for (int m = 0; m < KNN; ++m) op[m] = idx[m];
}

// ---------------- Kernel 2: gather + 3 MLPs + max over k (f32, unchanged) --------
__global__ __launch_bounds__(256) void agg_kernel(
    const float* __restrict__ pts,
    const float* __restrict__ feat,
    const float* __restrict__ w_geom,
    const float* __restrict__ g1, const float* __restrict__ b1,
    const float* __restrict__ m1, const float* __restrict__ v1,
    const float* __restrict__ w_sem,
    const float* __restrict__ g2, const float* __restrict__ b2,
    const float* __restrict__ m2, const float* __restrict__ v2,
    const float* __restrict__ w_fuse,
    const float* __restrict__ g3, const float* __restrict__ b3,
    const float* __restrict__ m3, const float* __restrict__ v3,
    const int* __restrict__ knn_idx,
    float* __restrict__ outp) {

    __shared__ alignas(16) unsigned short s_wsem[32][64][4];
    __shared__ alignas(16) unsigned short s_wfuse[32][64][4];
    __shared__ float s_wgeomT[6][64];
    __shared__ float s_s1[64], s_b1[64], s_s2[64], s_b2[64], s_s3[64], s_b3[64];
    __shared__ alignas(16) float s_ctrf[64];
    __shared__ float s_ctrp[4];
    __shared__ int   s_nidx[16];
    __shared__ float s_gdel[16][4];
    __shared__ alignas(16) float s_sdelta[16][64];
    __shared__ alignas(16) float s_mid[16][128];
    __shared__ float s_pmax[4][64];

    const int tid = threadIdx.x;

    for (int e = tid; e < 64 * 128; e += 256) {
        const int o = e >> 7, c = e & 127;
        s_wsem [c >> 2][o][c & 3] = f2bf(w_sem[e]);
        s_wfuse[c >> 2][o][c & 3] = f2bf(w_fuse[e]);
    }
    for (int e = tid; e < 64 * 6; e += 256) {
        const int o = e / 6, c = e - o * 6;
        s_wgeomT[c][o] = w_geom[e];
    }
    if (tid < 64) {
        float s;
        s = g1[tid] / sqrtf(v1[tid] + 1e-5f);
        s_s1[tid] = s; s_b1[tid] = b1[tid] - m1[tid] * s;
        s = g2[tid] / sqrtf(v2[tid] + 1e-5f);
        s_s2[tid] = s; s_b2[tid] = b2[tid] - m2[tid] * s;
        s = g3[tid] / sqrtf(v3[tid] + 1e-5f);
        s_s3[tid] = s; s_b3[tid] = b3[tid] - m3[tid] * s;
    }
    __syncthreads();

    const int o = tid & 63, kg = tid >> 6;

    for (int p = 0; p < 16; ++p) {
        const int pv = blockIdx.x * 16 + p;
        const int b = pv >> 13, n = pv & (NPTS - 1);
        const long pbase = (long)b * NPTS + n;

        if (tid < 16) s_nidx[tid] = knn_idx[pbase * KNN + tid];
        if (tid < 64) s_ctrf[tid] = feat[pbase * CH + tid];
        if (tid < 3)  s_ctrp[tid] = pts[pbase * 3 + tid];
        __syncthreads();

#pragma unroll
        for (int ki = 0; ki < 4; ++ki) {
            const int k = kg * 4 + ki;
            const long nb = (long)b * NPTS + s_nidx[k];
            s_sdelta[k][o] = feat[nb * CH + o] - s_ctrf[o];
        }
        if (tid < 16) {
            const long nb = (long)b * NPTS + s_nidx[tid];
            s_gdel[tid][0] = pts[nb * 3 + 0] - s_ctrp[0];
            s_gdel[tid][1] = pts[nb * 3 + 1] - s_ctrp[1];
            s_gdel[tid][2] = pts[nb * 3 + 2] - s_ctrp[2];
        }
        __syncthreads();

        float accc = 0.f;
#pragma unroll
        for (int qd = 0; qd < 16; ++qd) {
            const ushort4 w = *(const ushort4*)&s_wsem[qd][o][0];
            const float4 cv = *(const float4*)&s_ctrf[qd * 4];
            accc = fmaf(cv.x, bf2f(w.x), accc);
            accc = fmaf(cv.y, bf2f(w.y), accc);
            accc = fmaf(cv.z, bf2f(w.z), accc);
            accc = fmaf(cv.w, bf2f(w.w), accc);
        }
        float cg = s_ctrp[0] * s_wgeomT[0][o];
        cg = fmaf(s_ctrp[1], s_wgeomT[1][o], cg);
        cg = fmaf(s_ctrp[2], s_wgeomT[2][o], cg);

        const float s1o = s_s1[o], b1o = s_b1[o];
        const float s2o = s_s2[o], b2o = s_b2[o];

#pragma unroll
        for (int ki = 0; ki < 4; ++ki) {
            const int k = kg * 4 + ki;
            float g = cg;
            g = fmaf(s_gdel[k][0], s_wgeomT[3][o], g);
            g = fmaf(s_gdel[k][1], s_wgeomT[4][o], g);
            g = fmaf(s_gdel[k][2], s_wgeomT[5][o], g);
            const float gf = fmaxf(fmaf(g, s1o, b1o), 0.f);

            float a = accc;
#pragma unroll
            for (int qd = 0; qd < 16; ++qd) {
                const ushort4 w = *(const ushort4*)&s_wsem[16 + qd][o][0];
                const float4 dv = *(const float4*)&s_sdelta[k][qd * 4];
                a = fmaf(dv.x, bf2f(w.x), a);
                a = fmaf(dv.y, bf2f(w.y), a);
                a = fmaf(dv.z, bf2f(w.z), a);
                a = fmaf(dv.w, bf2f(w.w), a);
            }
            const float sf = fmaxf(fmaf(a, s2o, b2o), 0.f);
            s_mid[k][o] = gf;
            s_mid[k][64 + o] = sf;
        }
        __syncthreads();

        const float s3o = s_s3[o], b3o = s_b3[o];
        float fmx = 0.f;
#pragma unroll
        for (int ki = 0; ki < 4; ++ki) {
            const int k = kg * 4 + ki;
            float a = 0.f;
#pragma unroll
            for (int qd = 0; qd < 32; ++qd) {
                const ushort4 w = *(const ushort4*)&s_wfuse[qd][o][0];
                const float4 mv = *(const float4*)&s_mid[k][qd * 4];
                a = fmaf(mv.x, bf2f(w.x), a);
                a = fmaf(mv.y, bf2f(w.y), a);
                a = fmaf(mv.z, bf2f(w.z), a);
                a = fmaf(mv.w, bf2f(w.w), a);
            }
            const float fu = fmaxf(fmaf(a, s3o, b3o), 0.f);
            fmx = fmaxf(fmx, fu);
        }
        s_pmax[kg][o] = fmx;
        __syncthreads();

        if (tid < 64) {
            const float r = fmaxf(fmaxf(s_pmax[0][tid], s_pmax[1][tid]),
                                  fmaxf(s_pmax[2][tid], s_pmax[3][tid]));
            outp[pbase * CH + tid] = r;
        }
        __syncthreads();
    }
}

extern "C" void kernel_launch(void* const* d_in, const int* in_sizes, int n_in,
                              void* d_out, int out_size, void* d_ws, size_t ws_size,
                              hipStream_t stream) {
    (void)in_sizes; (void)n_in; (void)out_size;
    const float* pts    = (const float*)d_in[0];
    const float* feat   = (const float*)d_in[1];
    const float* w_geom = (const float*)d_in[2];
    const float* g1     = (const float*)d_in[3];
    const float* b1     = (const float*)d_in[4];
    const float* m1     = (const float*)d_in[5];
    const float* v1     = (const float*)d_in[6];
    const float* w_sem  = (const float*)d_in[7];
    const float* g2     = (const float*)d_in[8];
    const float* b2     = (const float*)d_in[9];
    const float* m2     = (const float*)d_in[10];
    const float* v2     = (const float*)d_in[11];
    const float* w_fuse = (const float*)d_in[12];
    const float* g3     = (const float*)d_in[13];
    const float* b3     = (const float*)d_in[14];
    const float* m3     = (const float*)d_in[15];
    const float* v3     = (const float*)d_in[16];

    int* idx_final = (int*)d_ws;                       // 32768*16*4 = 2 MB
    char* base = (char*)d_ws;

    if (ws_size >= (40ull << 20)) {
        // S=8: pdist 16MB @4MB, pidx 16MB @20MB
        float* pdist = (float*)(base + (4ull << 20));
        int*   pidx  = (int*)  (base + (20ull << 20));
        knn_part_kernel<8><<<dim3(256, 8), dim3(128), 0, stream>>>(pts, pdist, pidx);
        knn_merge_kernel<8><<<dim3(128), dim3(256), 0, stream>>>(pdist, pidx, idx_final);
    } else if (ws_size >= (21ull << 20)) {
        // S=4: pdist 8MB @4MB, pidx 8MB @12MB
        float* pdist = (float*)(base + (4ull << 20));
        int*   pidx  = (int*)  (base + (12ull << 20));
        knn_part_kernel<4><<<dim3(256, 4), dim3(128), 0, stream>>>(pts, pdist, pidx);
        knn_merge_kernel<4><<<dim3(128), dim3(256), 0, stream>>>(pdist, pidx, idx_final);
    } else {
        knn_full_kernel<<<dim3(256), dim3(128), 0, stream>>>(pts, idx_final);
    }

    agg_kernel<<<dim3(2048), dim3(256), 0, stream>>>(
        pts, feat, w_geom, g1, b1, m1, v1, w_sem, g2, b2, m2, v2,
        w_fuse, g3, b3, m3, v3, idx_final, (float*)d_out);
}

// Round 6
// 1294.079 us; speedup vs baseline: 1.8838x; 1.8838x over previous
//
#include <hip/hip_runtime.h>

#define NPTS 8192
#define NB 4
#define CH 64
#define KNN 16

__device__ __forceinline__ float bf2f(unsigned short u) {
    return __uint_as_float(((unsigned)u) << 16);
}
__device__ __forceinline__ unsigned short f2bf(float f) {
    unsigned u = __float_as_uint(f);
    u += 0x7fffu + ((u >> 16) & 1u);
    return (unsigned short)(u >> 16);
}

// sorted insertion of (d,i), strict < : lower-index-first on ties (ascending scan)
#define INSERT16(cd, ci, dist, idx)                         \
    {                                                       \
        float _cd = (cd); int _ci = (ci);                   \
        _Pragma("unroll")                                   \
        for (int m = 0; m < KNN; ++m) {                     \
            const bool sw = _cd < dist[m];                  \
            const float td = sw ? dist[m] : _cd;            \
            const int   ti = sw ? idx[m] : _ci;             \
            dist[m] = sw ? _cd : dist[m];                   \
            idx[m]  = sw ? _ci : idx[m];                    \
            _cd = td; _ci = ti;                             \
        }                                                   \
    }

// lexicographic (d,i) compare: true if (dB,iB) < (dA,iA)
__device__ __forceinline__ bool lex_lt(float dB, int iB, float dA, int iA) {
    return (dB < dA) || ((dB == dA) && (iB < iA));
}

// ---------------- Kernel 1: wave-per-query KNN, LDS butterfly merge ----------------
// 4 waves/block = 4 queries. Lane l scans candidates j = t*64+l keeping a per-lane
// sorted top-16; 6-level butterfly through LDS (lane-minor layout, 2-way aliasing
// only) merges the 64 lists exactly. No shfl, no cross-wave LDS sharing.
__global__ __launch_bounds__(256) void knn_wave_kernel(const float* __restrict__ pts,
                                                       int* __restrict__ idx_out) {
    __shared__ float s_d[4][KNN][64];
    __shared__ int   s_i[4][KNN][64];

    const int lane = threadIdx.x & 63;
    const int w    = threadIdx.x >> 6;
    const int q = blockIdx.x * 4 + w;           // 0..32767
    const int b = q >> 13;
    const int n = q & (NPTS - 1);
    const float* pb = pts + (size_t)b * NPTS * 3;

    const float px = pb[n * 3 + 0];
    const float py = pb[n * 3 + 1];
    const float pz = pb[n * 3 + 2];
    const float sqi = (px * px + py * py) + pz * pz;

    float dist[KNN];
    int   idx[KNN];
#pragma unroll
    for (int m = 0; m < KNN; ++m) { dist[m] = 3.4e38f; idx[m] = 0; }

    // scan: lane handles candidates lane, lane+64, ... (ascending -> strict-< insert
    // keeps (d, lower-index-first) order). Distance code verbatim from round-2 pass.
#pragma unroll 4
    for (int t = 0; t < NPTS / 64; ++t) {
        const int c = t * 64 + lane;
        const float x = pb[c * 3 + 0];
        const float y = pb[c * 3 + 1];
        const float z = pb[c * 3 + 2];
        const float sqj = (x * x + y * y) + z * z;
        float dot = px * x;
        dot = fmaf(py, y, dot);
        dot = fmaf(pz, z, dot);
        // d = (sq_i + sq_j) - 2*dot ; 2*dot exact so fma == separate rounding
        const float d = fmaf(dot, -2.0f, sqi + sqj);
        INSERT16(d, c, dist, idx);
    }

    // butterfly merge via LDS: after 6 levels every lane holds the global top-16.
#pragma unroll
    for (int stride = 1; stride < 64; stride <<= 1) {
        // publish own list (lane-minor: bank = lane%32, 2-way aliasing = free)
#pragma unroll
        for (int m = 0; m < KNN; ++m) {
            s_d[w][m][lane] = dist[m];
            s_i[w][m][lane] = idx[m];
        }
        __builtin_amdgcn_wave_barrier();   // pin write-before-read scheduling
        const int p = lane ^ stride;
        float bd[KNN]; int bi[KNN];
#pragma unroll
        for (int m = 0; m < KNN; ++m) {
            bd[m] = s_d[w][m][p];
            bi[m] = s_i[w][m][p];
        }
        __builtin_amdgcn_wave_barrier();   // pin read-before-next-level-write
        // min-merge with partner's reversed list: dist[m] = lexmin(A[m], B[15-m])
#pragma unroll
        for (int m = 0; m < KNN; ++m) {
            const float db = bd[15 - m];
            const int   ib = bi[15 - m];
            const bool bw = lex_lt(db, ib, dist[m], idx[m]);
            dist[m] = bw ? db : dist[m];
            idx[m]  = bw ? ib : idx[m];
        }
        // bitonic clean: stages 8,4,2,1 ascending
#pragma unroll
        for (int s = 8; s >= 1; s >>= 1) {
#pragma unroll
            for (int m = 0; m < KNN; ++m) {
                if ((m & s) == 0 && (m + s) < KNN) {
                    const float dA = dist[m], dB = dist[m + s];
                    const int   iA = idx[m],  iB = idx[m + s];
                    const bool sw = lex_lt(dB, iB, dA, iA);
                    dist[m]     = sw ? dB : dA;
                    dist[m + s] = sw ? dA : dB;
                    idx[m]      = sw ? iB : iA;
                    idx[m + s]  = sw ? iA : iB;
                }
            }
        }
    }

    if (lane == 0) {
        int* op = idx_out + (size_t)q * KNN;
#pragma unroll
        for (int m = 0; m < KNN; ++m) op[m] = idx[m];
    }
}

// ---------------- Kernel 2: gather + 3 MLPs + max over k (round-2 proven) ----------
__global__ __launch_bounds__(256) void agg_kernel(
    const float* __restrict__ pts,
    const float* __restrict__ feat,
    const float* __restrict__ w_geom,
    const float* __restrict__ g1, const float* __restrict__ b1,
    const float* __restrict__ m1, const float* __restrict__ v1,
    const float* __restrict__ w_sem,
    const float* __restrict__ g2, const float* __restrict__ b2,
    const float* __restrict__ m2, const float* __restrict__ v2,
    const float* __restrict__ w_fuse,
    const float* __restrict__ g3, const float* __restrict__ b3,
    const float* __restrict__ m3, const float* __restrict__ v3,
    const int* __restrict__ knn_idx,
    float* __restrict__ outp) {

    __shared__ alignas(16) unsigned short s_wsem[32][64][4];
    __shared__ alignas(16) unsigned short s_wfuse[32][64][4];
    __shared__ float s_wgeomT[6][64];
    __shared__ float s_s1[64], s_b1[64], s_s2[64], s_b2[64], s_s3[64], s_b3[64];
    __shared__ alignas(16) float s_ctrf[64];
    __shared__ float s_ctrp[4];
    __shared__ int   s_nidx[16];
    __shared__ float s_gdel[16][4];
    __shared__ alignas(16) float s_sdelta[16][64];
    __shared__ alignas(16) float s_mid[16][128];
    __shared__ float s_pmax[4][64];

    const int tid = threadIdx.x;

    for (int e = tid; e < 64 * 128; e += 256) {
        const int o = e >> 7, c = e & 127;
        s_wsem [c >> 2][o][c & 3] = f2bf(w_sem[e]);
        s_wfuse[c >> 2][o][c & 3] = f2bf(w_fuse[e]);
    }
    for (int e = tid; e < 64 * 6; e += 256) {
        const int o = e / 6, c = e - o * 6;
        s_wgeomT[c][o] = w_geom[e];
    }
    if (tid < 64) {
        float s;
        s = g1[tid] / sqrtf(v1[tid] + 1e-5f);
        s_s1[tid] = s; s_b1[tid] = b1[tid] - m1[tid] * s;
        s = g2[tid] / sqrtf(v2[tid] + 1e-5f);
        s_s2[tid] = s; s_b2[tid] = b2[tid] - m2[tid] * s;
        s = g3[tid] / sqrtf(v3[tid] + 1e-5f);
        s_s3[tid] = s; s_b3[tid] = b3[tid] - m3[tid] * s;
    }
    __syncthreads();

    const int o = tid & 63, kg = tid >> 6;

    for (int p = 0; p < 16; ++p) {
        const int pv = blockIdx.x * 16 + p;
        const int b = pv >> 13, n = pv & (NPTS - 1);
        const long pbase = (long)b * NPTS + n;

        if (tid < 16) s_nidx[tid] = knn_idx[pbase * KNN + tid];
        if (tid < 64) s_ctrf[tid] = feat[pbase * CH + tid];
        if (tid < 3)  s_ctrp[tid] = pts[pbase * 3 + tid];
        __syncthreads();

#pragma unroll
        for (int ki = 0; ki < 4; ++ki) {
            const int k = kg * 4 + ki;
            const long nb = (long)b * NPTS + s_nidx[k];
            s_sdelta[k][o] = feat[nb * CH + o] - s_ctrf[o];
        }
        if (tid < 16) {
            const long nb = (long)b * NPTS + s_nidx[tid];
            s_gdel[tid][0] = pts[nb * 3 + 0] - s_ctrp[0];
            s_gdel[tid][1] = pts[nb * 3 + 1] - s_ctrp[1];
            s_gdel[tid][2] = pts[nb * 3 + 2] - s_ctrp[2];
        }
        __syncthreads();

        float accc = 0.f;
#pragma unroll
        for (int qd = 0; qd < 16; ++qd) {
            const ushort4 w = *(const ushort4*)&s_wsem[qd][o][0];
            const float4 cv = *(const float4*)&s_ctrf[qd * 4];
            accc = fmaf(cv.x, bf2f(w.x), accc);
            accc = fmaf(cv.y, bf2f(w.y), accc);
            accc = fmaf(cv.z, bf2f(w.z), accc);
            accc = fmaf(cv.w, bf2f(w.w), accc);
        }
        float cg = s_ctrp[0] * s_wgeomT[0][o];
        cg = fmaf(s_ctrp[1], s_wgeomT[1][o], cg);
        cg = fmaf(s_ctrp[2], s_wgeomT[2][o], cg);

        const float s1o = s_s1[o], b1o = s_b1[o];
        const float s2o = s_s2[o], b2o = s_b2[o];

#pragma unroll
        for (int ki = 0; ki < 4; ++ki) {
            const int k = kg * 4 + ki;
            float g = cg;
            g = fmaf(s_gdel[k][0], s_wgeomT[3][o], g);
            g = fmaf(s_gdel[k][1], s_wgeomT[4][o], g);
            g = fmaf(s_gdel[k][2], s_wgeomT[5][o], g);
            const float gf = fmaxf(fmaf(g, s1o, b1o), 0.f);

            float a = accc;
#pragma unroll
            for (int qd = 0; qd < 16; ++qd) {
                const ushort4 w = *(const ushort4*)&s_wsem[16 + qd][o][0];
                const float4 dv = *(const float4*)&s_sdelta[k][qd * 4];
                a = fmaf(dv.x, bf2f(w.x), a);
                a = fmaf(dv.y, bf2f(w.y), a);
                a = fmaf(dv.z, bf2f(w.z), a);
                a = fmaf(dv.w, bf2f(w.w), a);
            }
            const float sf = fmaxf(fmaf(a, s2o, b2o), 0.f);
            s_mid[k][o] = gf;
            s_mid[k][64 + o] = sf;
        }
        __syncthreads();

        const float s3o = s_s3[o], b3o = s_b3[o];
        float fmx = 0.f;
#pragma unroll
        for (int ki = 0; ki < 4; ++ki) {
            const int k = kg * 4 + ki;
            float a = 0.f;
#pragma unroll
            for (int qd = 0; qd < 32; ++qd) {
                const ushort4 w = *(const ushort4*)&s_wfuse[qd][o][0];
                const float4 mv = *(const float4*)&s_mid[k][qd * 4];
                a = fmaf(mv.x, bf2f(w.x), a);
                a = fmaf(mv.y, bf2f(w.y), a);
                a = fmaf(mv.z, bf2f(w.z), a);
                a = fmaf(mv.w, bf2f(w.w), a);
            }
            const float fu = fmaxf(fmaf(a, s3o, b3o), 0.f);
            fmx = fmaxf(fmx, fu);
        }
        s_pmax[kg][o] = fmx;
        __syncthreads();

        if (tid < 64) {
            const float r = fmaxf(fmaxf(s_pmax[0][tid], s_pmax[1][tid]),
                                  fmaxf(s_pmax[2][tid], s_pmax[3][tid]));
            outp[pbase * CH + tid] = r;
        }
        __syncthreads();
    }
}

extern "C" void kernel_launch(void* const* d_in, const int* in_sizes, int n_in,
                              void* d_out, int out_size, void* d_ws, size_t ws_size,
                              hipStream_t stream) {
    (void)in_sizes; (void)n_in; (void)out_size; (void)ws_size;
    const float* pts    = (const float*)d_in[0];
    const float* feat   = (const float*)d_in[1];
    const float* w_geom = (const float*)d_in[2];
    const float* g1     = (const float*)d_in[3];
    const float* b1     = (const float*)d_in[4];
    const float* m1     = (const float*)d_in[5];
    const float* v1     = (const float*)d_in[6];
    const float* w_sem  = (const float*)d_in[7];
    const float* g2     = (const float*)d_in[8];
    const float* b2     = (const float*)d_in[9];
    const float* m2     = (const float*)d_in[10];
    const float* v2     = (const float*)d_in[11];
    const float* w_fuse = (const float*)d_in[12];
    const float* g3     = (const float*)d_in[13];
    const float* b3     = (const float*)d_in[14];
    const float* m3     = (const float*)d_in[15];
    const float* v3     = (const float*)d_in[16];

    int* idx_final = (int*)d_ws;   // 32768*16*4 = 2 MB

    knn_wave_kernel<<<dim3(NB * NPTS / 4), dim3(256), 0, stream>>>(pts, idx_final);

    agg_kernel<<<dim3(2048), dim3(256), 0, stream>>>(
        pts, feat, w_geom, g1, b1, m1, v1, w_sem, g2, b2, m2, v2,
        w_fuse, g3, b3, m3, v3, idx_final, (float*)d_out);
}